// Round 9
// baseline (743.560 us; speedup 1.0000x reference)
//
#include <hip/hip_runtime.h>
#include <math.h>

// MarketRegimeHMM forward via chunked associative scan — linear-domain semiring,
// base-2 scales.  R8: k_build rewritten with ZERO ARRAYS — every E/R entry is a
// named scalar generated by macros.  R5/R6/R7 all hit scratch (0.4-3 GB excess
// HBM traffic) whenever C arrays were passed through inlined pointer params;
// named scalars make register residency structural, not an SROA gamble.
//
//   k_prep  : 1 block; params -> padded vector layout (race-free, disjoint
//             index ranges; R7 had a pad-write race into Q_W1).
//   k_build : one lane per chunk (C=4), params in 3KB LDS (broadcast float4
//             reads), 4 straight-line steps: build E (named scalars) ->
//             pack bf16 -> fold (125 FMA) -> rescale-by-max.
//   k_scan  : one block per b: 3-level scan over 1024 records -> start, LL.
//   k_alpha : one lane per chunk: stream bf16 E, 25 FMA + 5 log2 per t.

namespace {

constexpr int kS = 5, kD = 16, kB = 256, kT = 4096;
constexpr int kC = 4, kNC = 1024;  // chunks per batch element

constexpr float kL2E = 1.4426950408889634f;  // 1/ln2
constexpr float kLn2 = 0.6931471805599453f;

// LDS/ws param layout (floats), all vector-read aligned:
constexpr int Q_MU = 0;    // 80  means                      [s*16+d]   float4
constexpr int Q_EA = 80;   // 80  -0.5*inv_v/ln2             [s*16+d]   float4
constexpr int Q_EC = 160;  // 5   -0.5*(16ln2pi+sum lv)/ln2  scalar
constexpr int Q_LN = 168;  // 5   log2_softmax(log_initial)  scalar
constexpr int Q_W1 = 176;  // 200 (2/ln2)*W1                 [(i*10+h)*4+f] float4
constexpr int Q_B1 = 376;  // 60  (2/ln2)*b1, rows of 12     f4,f4,f2
constexpr int Q_W2 = 436;  // 300 W2/ln2 rows of 12; slot10=(b2+tb)/ln2  3x float4
constexpr int P_TOT = 768;   // staged floats (3KB)
constexpr int P_RSV = 1024;  // reserved in ws

__device__ __forceinline__ float max5(float a0, float a1, float a2, float a3, float a4) {
  return fmaxf(fmaxf(fmaxf(a0, a1), fmaxf(a2, a3)), a4);
}

__device__ __forceinline__ unsigned bf16bits(float x) {
  unsigned u = __float_as_uint(x);
  return (u + 0x7fffu + ((u >> 16) & 1u)) >> 16;  // RTNE
}

__global__ void k_prep(const float* __restrict__ means, const float* __restrict__ lv,
                       const float* __restrict__ linit, const float* __restrict__ tbias,
                       const float* __restrict__ W1g, const float* __restrict__ b1g,
                       const float* __restrict__ W2g, const float* __restrict__ b2g,
                       float* __restrict__ P) {
  const int tid = threadIdx.x;  // 256; all target ranges disjoint -> no races
  if (tid < 80) {
    P[Q_MU + tid] = means[tid];
    P[Q_EA + tid] = -0.5f * kL2E * __expf(-lv[tid]);
  }
  if (tid >= 80 && tid < 85) {
    const int s = tid - 80;
    float acc = 0.f;
#pragma unroll
    for (int d = 0; d < 16; ++d) acc += lv[s * 16 + d];
    P[Q_EC + s] = -0.5f * kL2E * (29.406033062549525f + acc);  // 16*ln(2pi)+sum
    const float l0 = linit[0], l1 = linit[1], l2 = linit[2], l3 = linit[3], l4 = linit[4];
    const float m = max5(l0, l1, l2, l3, l4);
    const float se = __expf(l0 - m) + __expf(l1 - m) + __expf(l2 - m) +
                     __expf(l3 - m) + __expf(l4 - m);
    P[Q_LN + s] = kL2E * (linit[s] - (m + __logf(se)));
  }
  for (int i = tid; i < 200; i += 256) P[Q_W1 + i] = (2.0f * kL2E) * W1g[i];
  if (tid < 60) {
    const int r = tid / 12, h = tid - r * 12;
    P[Q_B1 + tid] = (h < 10) ? (2.0f * kL2E) * b1g[r * 10 + h] : 0.f;
  }
  for (int i = tid; i < 300; i += 256) {
    const int r = i / 12, h = i - r * 12;
    float v;
    if (h < 10) v = kL2E * W2g[r * 10 + h];
    else if (h == 10) v = kL2E * (b2g[r] + tbias[r]);
    else v = 0.f;
    P[Q_W2 + i] = v;
  }
}

// ---------- named-scalar macros for k_build ----------

#define LOAD_O(t)                                                               \
  const float4* _op = reinterpret_cast<const float4*>(obs + (size_t)(t) * 16);  \
  const float4 _oa = _op[0], _obv = _op[1], _ocv = _op[2], _odv = _op[3];       \
  const float ob0 = _oa.x, ob1 = _oa.y, ob2 = _oa.z, ob3 = _oa.w,              \
              ob4 = _obv.x, ob5 = _obv.y, ob6 = _obv.z, ob7 = _obv.w,          \
              ob8 = _ocv.x, ob9 = _ocv.y, ob10 = _ocv.z, ob11 = _ocv.w,        \
              ob12 = _odv.x, ob13 = _odv.y, ob14 = _odv.z, ob15 = _odv.w;

#define EMITQ(s, dq, A, B, C, Dd)                                               \
  {                                                                             \
    const float4 mu = *reinterpret_cast<const float4*>(p + Q_MU + (s)*16 + (dq)*4); \
    const float4 ea = *reinterpret_cast<const float4*>(p + Q_EA + (s)*16 + (dq)*4); \
    const float d0 = (A) - mu.x, d1 = (B) - mu.y, d2 = (C) - mu.z, d3 = (Dd) - mu.w; \
    acc = fmaf(d0 * d0, ea.x, acc); acc = fmaf(d1 * d1, ea.y, acc);             \
    acc = fmaf(d2 * d2, ea.z, acc); acc = fmaf(d3 * d3, ea.w, acc);             \
  }

#define EMIT(s)                                                                 \
  float le##s;                                                                  \
  {                                                                             \
    float acc = p[Q_EC + (s)];                                                  \
    EMITQ(s, 0, ob0, ob1, ob2, ob3)                                             \
    EMITQ(s, 1, ob4, ob5, ob6, ob7)                                             \
    EMITQ(s, 2, ob8, ob9, ob10, ob11)                                           \
    EMITQ(s, 3, ob12, ob13, ob14, ob15)                                         \
    le##s = acc;                                                                \
  }

#define HV1(i, h, BSRC)                                                         \
  float hv##h;                                                                  \
  {                                                                             \
    const float4 w = *reinterpret_cast<const float4*>(p + Q_W1 + ((i)*10 + (h)) * 4); \
    float acc = (BSRC);                                                         \
    acc = fmaf(fx, w.x, acc); acc = fmaf(fy, w.y, acc);                         \
    acc = fmaf(fz, w.z, acc); acc = fmaf(fw, w.w, acc);                         \
    const float ex = exp2f(acc); /* = exp(2x), weights pre-scaled */            \
    hv##h = 1.f - 2.f * __builtin_amdgcn_rcpf(ex + 1.f); /* tanh */             \
  }

#define LOGIT(i, j)                                                             \
  float eg##j;                                                                  \
  {                                                                             \
    const float* wr = p + Q_W2 + ((i)*5 + (j)) * 12;                            \
    const float4 w0 = *reinterpret_cast<const float4*>(wr);                     \
    const float4 w1 = *reinterpret_cast<const float4*>(wr + 4);                 \
    const float4 w2 = *reinterpret_cast<const float4*>(wr + 8); /* x=w8 y=w9 z=b2 */ \
    float acc = w2.z;                                                           \
    acc = fmaf(hv0, w0.x, acc); acc = fmaf(hv1, w0.y, acc);                     \
    acc = fmaf(hv2, w0.z, acc); acc = fmaf(hv3, w0.w, acc);                     \
    acc = fmaf(hv4, w1.x, acc); acc = fmaf(hv5, w1.y, acc);                     \
    acc = fmaf(hv6, w1.z, acc); acc = fmaf(hv7, w1.w, acc);                     \
    acc = fmaf(hv8, w2.x, acc); acc = fmaf(hv9, w2.y, acc);                     \
    eg##j = exp2f(acc);                                                         \
  }

#define BUILD_STATE(i)                                                          \
  {                                                                             \
    const float4 bA = *reinterpret_cast<const float4*>(p + Q_B1 + (i)*12);      \
    const float4 bB = *reinterpret_cast<const float4*>(p + Q_B1 + (i)*12 + 4);  \
    const float2 bC = *reinterpret_cast<const float2*>(p + Q_B1 + (i)*12 + 8);  \
    HV1(i, 0, bA.x) HV1(i, 1, bA.y) HV1(i, 2, bA.z) HV1(i, 3, bA.w)             \
    HV1(i, 4, bB.x) HV1(i, 5, bB.y) HV1(i, 6, bB.z) HV1(i, 7, bB.w)             \
    HV1(i, 8, bC.x) HV1(i, 9, bC.y)                                             \
    LOGIT(i, 0) LOGIT(i, 1) LOGIT(i, 2) LOGIT(i, 3) LOGIT(i, 4)                 \
    const float rs = __builtin_amdgcn_rcpf(eg0 + eg1 + eg2 + eg3 + eg4);        \
    E##i##0 = eg0 * rs * eml0; E##i##1 = eg1 * rs * eml1;                       \
    E##i##2 = eg2 * rs * eml2; E##i##3 = eg3 * rs * eml3;                       \
    E##i##4 = eg4 * rs * eml4;                                                  \
  }

#define BUILD_E(t)                                                              \
  LOAD_O(t)                                                                     \
  EMIT(0) EMIT(1) EMIT(2) EMIT(3) EMIT(4)                                       \
  cE = max5(le0, le1, le2, le3, le4);                                           \
  const float eml0 = exp2f(le0 - cE), eml1 = exp2f(le1 - cE),                   \
              eml2 = exp2f(le2 - cE), eml3 = exp2f(le3 - cE),                   \
              eml4 = exp2f(le4 - cE);                                           \
  const float4 _fv = *reinterpret_cast<const float4*>(feat + (size_t)(t) * 4);  \
  const float fx = _fv.x, fy = _fv.y, fz = _fv.z, fw = _fv.w;                   \
  BUILD_STATE(0) BUILD_STATE(1) BUILD_STATE(2) BUILD_STATE(3) BUILD_STATE(4)

#define PACK_E(t)                                                               \
  if (STORE_E) {                                                                \
    uint4* wp = wsE + (size_t)(t) * 4;                                          \
    wp[0] = make_uint4(bf16bits(E00) | (bf16bits(E01) << 16),                   \
                       bf16bits(E02) | (bf16bits(E03) << 16),                   \
                       bf16bits(E04) | (bf16bits(E10) << 16),                   \
                       bf16bits(E11) | (bf16bits(E12) << 16));                  \
    wp[1] = make_uint4(bf16bits(E13) | (bf16bits(E14) << 16),                   \
                       bf16bits(E20) | (bf16bits(E21) << 16),                   \
                       bf16bits(E22) | (bf16bits(E23) << 16),                   \
                       bf16bits(E24) | (bf16bits(E30) << 16));                  \
    wp[2] = make_uint4(bf16bits(E31) | (bf16bits(E32) << 16),                   \
                       bf16bits(E33) | (bf16bits(E34) << 16),                   \
                       bf16bits(E40) | (bf16bits(E41) << 16),                   \
                       bf16bits(E42) | (bf16bits(E43) << 16));                  \
    const unsigned cb = __float_as_uint(cE);                                    \
    wp[3] = make_uint4(bf16bits(E44) | (cb << 16), cb >> 16, 0u, 0u);           \
  }

#define FOLD_ROW(i)                                                             \
  {                                                                             \
    const float n0 = fmaf(R##i##0, E00, fmaf(R##i##1, E10, fmaf(R##i##2, E20, fmaf(R##i##3, E30, R##i##4 * E40)))); \
    const float n1 = fmaf(R##i##0, E01, fmaf(R##i##1, E11, fmaf(R##i##2, E21, fmaf(R##i##3, E31, R##i##4 * E41)))); \
    const float n2 = fmaf(R##i##0, E02, fmaf(R##i##1, E12, fmaf(R##i##2, E22, fmaf(R##i##3, E32, R##i##4 * E42)))); \
    const float n3 = fmaf(R##i##0, E03, fmaf(R##i##1, E13, fmaf(R##i##2, E23, fmaf(R##i##3, E33, R##i##4 * E43)))); \
    const float n4 = fmaf(R##i##0, E04, fmaf(R##i##1, E14, fmaf(R##i##2, E24, fmaf(R##i##3, E34, R##i##4 * E44)))); \
    R##i##0 = n0; R##i##1 = n1; R##i##2 = n2; R##i##3 = n3; R##i##4 = n4;       \
  }

#define FOLD_ALL FOLD_ROW(0) FOLD_ROW(1) FOLD_ROW(2) FOLD_ROW(3) FOLD_ROW(4)

#define RESCALE25                                                               \
  {                                                                             \
    float _m = fmaxf(R00, R01); _m = fmaxf(_m, R02); _m = fmaxf(_m, R03);       \
    _m = fmaxf(_m, R04); _m = fmaxf(_m, R10); _m = fmaxf(_m, R11);              \
    _m = fmaxf(_m, R12); _m = fmaxf(_m, R13); _m = fmaxf(_m, R14);              \
    _m = fmaxf(_m, R20); _m = fmaxf(_m, R21); _m = fmaxf(_m, R22);              \
    _m = fmaxf(_m, R23); _m = fmaxf(_m, R24); _m = fmaxf(_m, R30);              \
    _m = fmaxf(_m, R31); _m = fmaxf(_m, R32); _m = fmaxf(_m, R33);              \
    _m = fmaxf(_m, R34); _m = fmaxf(_m, R40); _m = fmaxf(_m, R41);              \
    _m = fmaxf(_m, R42); _m = fmaxf(_m, R43); _m = fmaxf(_m, R44);              \
    _m = fmaxf(_m, 1e-30f);                                                     \
    const float _rr = __builtin_amdgcn_rcpf(_m);                                \
    R00 *= _rr; R01 *= _rr; R02 *= _rr; R03 *= _rr; R04 *= _rr;                 \
    R10 *= _rr; R11 *= _rr; R12 *= _rr; R13 *= _rr; R14 *= _rr;                 \
    R20 *= _rr; R21 *= _rr; R22 *= _rr; R23 *= _rr; R24 *= _rr;                 \
    R30 *= _rr; R31 *= _rr; R32 *= _rr; R33 *= _rr; R34 *= _rr;                 \
    R40 *= _rr; R41 *= _rr; R42 *= _rr; R43 *= _rr; R44 *= _rr;                 \
    sc += __log2f(_m);                                                          \
  }

template <bool STORE_E>
__global__ __launch_bounds__(256, 2) void k_build(
    const float* __restrict__ obs, const float* __restrict__ feat,
    const float* __restrict__ P, float* __restrict__ Rg,
    uint4* __restrict__ wsE) {
  __shared__ __align__(16) float p[P_TOT];
  if (threadIdx.x < P_TOT / 4)
    reinterpret_cast<float4*>(p)[threadIdx.x] =
        reinterpret_cast<const float4*>(P)[threadIdx.x];
  __syncthreads();
  const int gc = blockIdx.x * 256 + threadIdx.x;  // chunk id
  const int b = gc >> 10, cc = gc & (kNC - 1);
  const size_t t0 = (size_t)b * kT + (size_t)cc * kC;
  float E00, E01, E02, E03, E04, E10, E11, E12, E13, E14,
        E20, E21, E22, E23, E24, E30, E31, E32, E33, E34,
        E40, E41, E42, E43, E44;
  float R00, R01, R02, R03, R04, R10, R11, R12, R13, R14,
        R20, R21, R22, R23, R24, R30, R31, R32, R33, R34,
        R40, R41, R42, R43, R44;
  float sc, cE;
  {  // step 0 (t0): either the alpha0 pseudo-record or a normal E
    LOAD_O(t0)
    EMIT(0) EMIT(1) EMIT(2) EMIT(3) EMIT(4)
    if (cc == 0) {
      const float v0 = le0 + p[Q_LN + 0], v1 = le1 + p[Q_LN + 1];
      const float v2 = le2 + p[Q_LN + 2], v3 = le3 + p[Q_LN + 3];
      const float v4 = le4 + p[Q_LN + 4];
      cE = max5(v0, v1, v2, v3, v4);
      const float g0 = 0.2f * exp2f(v0 - cE), g1 = 0.2f * exp2f(v1 - cE);
      const float g2 = 0.2f * exp2f(v2 - cE), g3 = 0.2f * exp2f(v3 - cE);
      const float g4 = 0.2f * exp2f(v4 - cE);
      E00 = g0; E01 = g1; E02 = g2; E03 = g3; E04 = g4;
      E10 = g0; E11 = g1; E12 = g2; E13 = g3; E14 = g4;
      E20 = g0; E21 = g1; E22 = g2; E23 = g3; E24 = g4;
      E30 = g0; E31 = g1; E32 = g2; E33 = g3; E34 = g4;
      E40 = g0; E41 = g1; E42 = g2; E43 = g3; E44 = g4;
    } else {
      cE = max5(le0, le1, le2, le3, le4);
      const float eml0 = exp2f(le0 - cE), eml1 = exp2f(le1 - cE),
                  eml2 = exp2f(le2 - cE), eml3 = exp2f(le3 - cE),
                  eml4 = exp2f(le4 - cE);
      const float4 _fv = *reinterpret_cast<const float4*>(feat + t0 * 4);
      const float fx = _fv.x, fy = _fv.y, fz = _fv.z, fw = _fv.w;
      BUILD_STATE(0) BUILD_STATE(1) BUILD_STATE(2) BUILD_STATE(3) BUILD_STATE(4)
    }
    PACK_E(t0)
  }
  R00 = E00; R01 = E01; R02 = E02; R03 = E03; R04 = E04;
  R10 = E10; R11 = E11; R12 = E12; R13 = E13; R14 = E14;
  R20 = E20; R21 = E21; R22 = E22; R23 = E23; R24 = E24;
  R30 = E30; R31 = E31; R32 = E32; R33 = E33; R34 = E34;
  R40 = E40; R41 = E41; R42 = E42; R43 = E43; R44 = E44;
  sc = cE;
  { BUILD_E(t0 + 1) PACK_E(t0 + 1) }
  sc += cE;
  FOLD_ALL
  RESCALE25
  { BUILD_E(t0 + 2) PACK_E(t0 + 2) }
  sc += cE;
  FOLD_ALL
  RESCALE25
  { BUILD_E(t0 + 3) PACK_E(t0 + 3) }
  sc += cE;
  FOLD_ALL
  RESCALE25
  float4* o4 = reinterpret_cast<float4*>(Rg + (size_t)gc * 28);
  o4[0] = make_float4(R00, R01, R02, R03);
  o4[1] = make_float4(R04, R10, R11, R12);
  o4[2] = make_float4(R13, R14, R20, R21);
  o4[3] = make_float4(R22, R23, R24, R30);
  o4[4] = make_float4(R31, R32, R33, R34);
  o4[5] = make_float4(R40, R41, R42, R43);
  o4[6] = make_float4(R44, sc, 0.f, 0.f);
}

// ---------- scan / alpha (array forms proven fine in these kernels) ----------

__device__ __forceinline__ void matmat5(float R[25], const float E[25]) {
#pragma unroll
  for (int i = 0; i < 5; ++i) {
    const float r0 = R[i * 5 + 0], r1 = R[i * 5 + 1], r2 = R[i * 5 + 2];
    const float r3 = R[i * 5 + 3], r4 = R[i * 5 + 4];
#pragma unroll
    for (int j = 0; j < 5; ++j) {
      float acc = r0 * E[j];
      acc = fmaf(r1, E[5 + j], acc);
      acc = fmaf(r2, E[10 + j], acc);
      acc = fmaf(r3, E[15 + j], acc);
      acc = fmaf(r4, E[20 + j], acc);
      R[i * 5 + j] = acc;
    }
  }
}

__device__ __forceinline__ void rescale25a(float R[25], float& sc) {
  float m = R[0];
#pragma unroll
  for (int e = 1; e < 25; ++e) m = fmaxf(m, R[e]);
  m = fmaxf(m, 1e-30f);
  const float r = __builtin_amdgcn_rcpf(m);
#pragma unroll
  for (int e = 0; e < 25; ++e) R[e] *= r;
  sc += __log2f(m);
}

__device__ __forceinline__ void vecmat5(float a[5], const float M[25]) {
  float o[5];
#pragma unroll
  for (int j = 0; j < 5; ++j) {
    float acc = a[0] * M[j];
    acc = fmaf(a[1], M[5 + j], acc);
    acc = fmaf(a[2], M[10 + j], acc);
    acc = fmaf(a[3], M[15 + j], acc);
    acc = fmaf(a[4], M[20 + j], acc);
    o[j] = acc;
  }
#pragma unroll
  for (int j = 0; j < 5; ++j) a[j] = o[j];
}

__device__ __forceinline__ void rescale5(float a[5], float& ls) {
  const float m = fmaxf(max5(a[0], a[1], a[2], a[3], a[4]), 1e-30f);
  const float r = __builtin_amdgcn_rcpf(m);
#pragma unroll
  for (int j = 0; j < 5; ++j) a[j] *= r;
  ls += __log2f(m);
}

__device__ __forceinline__ void loadRec(const float* __restrict__ base, size_t rec,
                                        float M[25], float& msc) {
  const float4* src = reinterpret_cast<const float4*>(base + rec * 28);
  float4 q[7];
#pragma unroll
  for (int i = 0; i < 7; ++i) q[i] = src[i];
  const float* v = reinterpret_cast<const float*>(q);
#pragma unroll
  for (int e = 0; e < 25; ++e) M[e] = v[e];
  msc = v[25];
}

// 3-level scan over 1024 records per b -> start[b][c], LL[b].
__global__ __launch_bounds__(256) void k_scan(const float* __restrict__ Rg,
                                              float* __restrict__ start,
                                              float* __restrict__ out) {
  __shared__ float sA[256 * 29];
  __shared__ float sB[32 * 28];
  __shared__ float sPB[32 * 8];
  __shared__ float sPA[256 * 8];
  const int b = blockIdx.x, j = threadIdx.x;
  const float* Rb = Rg + (size_t)b * kNC * 28;
  float A[25], asc;
  loadRec(Rb, (size_t)(4 * j), A, asc);
#pragma unroll 1
  for (int k = 1; k < 4; ++k) {
    float M[25], msc;
    loadRec(Rb, (size_t)(4 * j + k), M, msc);
    asc += msc;
    matmat5(A, M);
    if (k >= 2) rescale25a(A, asc);
  }
#pragma unroll
  for (int e = 0; e < 25; ++e) sA[j * 29 + e] = A[e];
  sA[j * 29 + 25] = asc;
  __syncthreads();
  if (j < 32) {
    float Bm[25], bsc;
#pragma unroll
    for (int e = 0; e < 25; ++e) Bm[e] = sA[(8 * j) * 29 + e];
    bsc = sA[(8 * j) * 29 + 25];
#pragma unroll 1
    for (int k = 1; k < 8; ++k) {
      float M[25];
#pragma unroll
      for (int e = 0; e < 25; ++e) M[e] = sA[(8 * j + k) * 29 + e];
      bsc += sA[(8 * j + k) * 29 + 25];
      matmat5(Bm, M);
      if (k & 1) rescale25a(Bm, bsc);
    }
#pragma unroll
    for (int e = 0; e < 25; ++e) sB[j * 28 + e] = Bm[e];
    sB[j * 28 + 25] = bsc;
  }
  __syncthreads();
  if (j == 0) {
    float a[5] = {1.f, 1.f, 1.f, 1.f, 1.f};
    float ls = 0.f;
#pragma unroll 1
    for (int g = 0; g < 32; ++g) {
#pragma unroll
      for (int s = 0; s < 5; ++s) sPB[g * 8 + s] = a[s];
      sPB[g * 8 + 5] = ls;
      float M[25];
#pragma unroll
      for (int e = 0; e < 25; ++e) M[e] = sB[g * 28 + e];
      vecmat5(a, M);
      ls += sB[g * 28 + 25];
      rescale5(a, ls);
    }
    out[b] = (__log2f(a[0] + a[1] + a[2] + a[3] + a[4]) + ls) * kLn2;
  }
  __syncthreads();
  if (j < 32) {
    float a[5], ls;
#pragma unroll
    for (int s = 0; s < 5; ++s) a[s] = sPB[j * 8 + s];
    ls = sPB[j * 8 + 5];
#pragma unroll 1
    for (int q = 0; q < 8; ++q) {
      const int idx = 8 * j + q;
#pragma unroll
      for (int s = 0; s < 5; ++s) sPA[idx * 8 + s] = a[s];
      sPA[idx * 8 + 5] = ls;
      float M[25];
#pragma unroll
      for (int e = 0; e < 25; ++e) M[e] = sA[idx * 29 + e];
      vecmat5(a, M);
      ls += sA[idx * 29 + 25];
      rescale5(a, ls);
    }
  }
  __syncthreads();
  {
    float a[5], ls;
#pragma unroll
    for (int s = 0; s < 5; ++s) a[s] = sPA[j * 8 + s];
    ls = sPA[j * 8 + 5];
#pragma unroll 1
    for (int k = 0; k < 4; ++k) {
      const int r = 4 * j + k;
      float* st = start + ((size_t)b * kNC + r) * 8;
      reinterpret_cast<float4*>(st)[0] = make_float4(a[0], a[1], a[2], a[3]);
      reinterpret_cast<float4*>(st)[1] = make_float4(a[4], ls, 0.f, 0.f);
      float M[25], msc;
      loadRec(Rb, (size_t)r, M, msc);
      vecmat5(a, M);
      ls += msc;
      rescale5(a, ls);
    }
  }
}

// stream bf16 E records; one lane per chunk
__global__ __launch_bounds__(256) void k_alpha_a(const uint4* __restrict__ wsE,
                                                 const float* __restrict__ start,
                                                 float* __restrict__ outp) {
  const int gc = blockIdx.x * 256 + threadIdx.x;
  const int b = gc >> 10, cc = gc & (kNC - 1);
  const float* st = start + (size_t)gc * 8;
  const float4 s0 = reinterpret_cast<const float4*>(st)[0];
  const float4 s1 = reinterpret_cast<const float4*>(st)[1];
  float a[5] = {s0.x, s0.y, s0.z, s0.w, s1.x};
  float ls = s1.y;
  float ov[20];
  const uint4* ep = wsE + ((size_t)b * kT + (size_t)cc * kC) * 4;
#pragma unroll
  for (int k = 0; k < 4; ++k) {
    uint4 q0 = ep[k * 4], q1 = ep[k * 4 + 1], q2 = ep[k * 4 + 2], q3 = ep[k * 4 + 3];
    unsigned d[14] = {q0.x, q0.y, q0.z, q0.w, q1.x, q1.y, q1.z, q1.w,
                      q2.x, q2.y, q2.z, q2.w, q3.x, q3.y};
    float E[25];
#pragma unroll
    for (int q = 0; q < 12; ++q) {
      E[2 * q]     = __uint_as_float(d[q] << 16);
      E[2 * q + 1] = __uint_as_float(d[q] & 0xffff0000u);
    }
    E[24] = __uint_as_float(d[12] << 16);
    const float cst = __uint_as_float((d[12] >> 16) | (d[13] << 16));
    float o[5];
#pragma unroll
    for (int j = 0; j < 5; ++j) {
      float acc = a[0] * E[j];
      acc = fmaf(a[1], E[5 + j], acc);
      acc = fmaf(a[2], E[10 + j], acc);
      acc = fmaf(a[3], E[15 + j], acc);
      acc = fmaf(a[4], E[20 + j], acc);
      o[j] = acc;
    }
    ls += cst;
    float L[5];
#pragma unroll
    for (int j = 0; j < 5; ++j) L[j] = __log2f(o[j]);
#pragma unroll
    for (int j = 0; j < 5; ++j) ov[k * 5 + j] = (L[j] + ls) * kLn2;
    const float lm = max5(L[0], L[1], L[2], L[3], L[4]);
    const float m = fmaxf(max5(o[0], o[1], o[2], o[3], o[4]), 1e-30f);
    const float r = __builtin_amdgcn_rcpf(m);
#pragma unroll
    for (int j = 0; j < 5; ++j) a[j] = o[j] * r;
    ls += lm;
  }
  float4* w = reinterpret_cast<float4*>(outp + kB + ((size_t)b * kT + (size_t)cc * kC) * kS);
#pragma unroll
  for (int q = 0; q < 5; ++q)
    w[q] = make_float4(ov[q * 4], ov[q * 4 + 1], ov[q * 4 + 2], ov[q * 4 + 3]);
}

}  // namespace

extern "C" void kernel_launch(void* const* d_in, const int* in_sizes, int n_in,
                              void* d_out, int out_size, void* d_ws, size_t ws_size,
                              hipStream_t stream) {
  (void)in_sizes; (void)n_in; (void)out_size; (void)ws_size;
  const float* obs   = (const float*)d_in[0];
  const float* feat  = (const float*)d_in[1];
  const float* means = (const float*)d_in[2];
  const float* lv    = (const float*)d_in[3];
  const float* linit = (const float*)d_in[4];
  const float* tbias = (const float*)d_in[5];
  const float* W1g   = (const float*)d_in[6];
  const float* b1g   = (const float*)d_in[7];
  const float* W2g   = (const float*)d_in[8];
  const float* b2g   = (const float*)d_in[9];
  float* out = (float*)d_out;

  // ws layout (floats): P 1024 | Rg kB*kNC*28 | start kB*kNC*8 | wsE (bytes)
  float* P     = (float*)d_ws;
  float* Rg    = P + P_RSV;
  float* start = Rg + (size_t)kB * kNC * 28;
  uint4* wsE   = reinterpret_cast<uint4*>(start + (size_t)kB * kNC * 8);

  const int nBlk = (kB * kNC) / 256;  // 1024
  k_prep<<<1, 256, 0, stream>>>(means, lv, linit, tbias, W1g, b1g, W2g, b2g, P);
  k_build<true><<<nBlk, 256, 0, stream>>>(obs, feat, P, Rg, wsE);
  k_scan<<<kB, 256, 0, stream>>>(Rg, start, out);
  k_alpha_a<<<nBlk, 256, 0, stream>>>(wsE, start, out);
}

// Round 10
// 124.799 us; speedup vs baseline: 5.9581x; 5.9581x over previous
//
#include <hip/hip_runtime.h>
#include <math.h>

// MarketRegimeHMM forward via chunked associative scan — linear semiring,
// base-2 scales.  R9 = R3/R4 phase-split skeleton (the ONLY structure that
// never spilled: build phase holds E only, fold phase holds R-rows only;
// VGPR 56) + three arithmetic trims in buildE:
//   1. expanded emission quadratic (o2 shared across states)
//   2. tanh folded into W2 (logits = b2' + W2'.r, r = rcp(e+1))
//   3. v_cvt_pk_bf16_f32 packing (12 instrs vs ~110 bit-twiddles)
//
//   k_prep  : 1 block; params -> vector layout in ws (incl. W2 row sums).
//   k_build : 256 t per block; thread t builds E_t; swizzled LDS transpose;
//             8 lanes/chunk row-parallel fold of 8 steps -> R[b][c].
//   k_scan  : one block per b; 512-record scan -> start[b][c], LL[b].
//   k_alpha : one lane per chunk: stream bf16 E, 25 FMA + 5 log2 per t.

namespace {

constexpr int kS = 5, kD = 16, kB = 256, kT = 4096;
constexpr int kC = 8, kNC = 512;     // chunks per batch element
constexpr int kTile = 256, kCPT = 32;
constexpr int kG = 16, kNG = 32;

constexpr float kL2E = 1.4426950408889634f;  // 1/ln2
constexpr float kLn2 = 0.6931471805599453f;

// param layout (floats), all vector-read aligned:
constexpr int L_QA = 0;    // 80  -0.5*inv_v/ln2           [s*16+d] float4
constexpr int L_QB = 80;   // 80  mu*inv_v/ln2             [s*16+d] float4
constexpr int L_QC = 160;  // 5   -0.5/ln2*(16ln2pi + sum(lv + iv*mu^2))
constexpr int L_LN = 168;  // 5   log2_softmax(log_initial)
constexpr int L_W1 = 176;  // 200 (2/ln2)*W1               [(i*10+h)*4+f] float4
constexpr int L_B1 = 376;  // 60  (2/ln2)*b1, rows of 12   f4,f4,f2
constexpr int L_W2 = 436;  // 300 rows of 12: 0..9 = -2*W2/ln2,
                           //     10 = (b2+tb+sum_h W2)/ln2, 11 = 0
constexpr int P_TOT = 768;   // staged floats (3KB)
constexpr int P_RSV = 1024;  // reserved in ws

__device__ __forceinline__ float max5(float a0, float a1, float a2, float a3, float a4) {
  return fmaxf(fmaxf(fmaxf(a0, a1), fmaxf(a2, a3)), a4);
}

__device__ __forceinline__ void loadObs(const float* __restrict__ obs_bt, float* o) {
  const float4* o4 = reinterpret_cast<const float4*>(obs_bt);
  float4 v0 = o4[0], v1 = o4[1], v2 = o4[2], v3 = o4[3];
  o[0] = v0.x; o[1] = v0.y; o[2] = v0.z; o[3] = v0.w;
  o[4] = v1.x; o[5] = v1.y; o[6] = v1.z; o[7] = v1.w;
  o[8] = v2.x; o[9] = v2.y; o[10] = v2.z; o[11] = v2.w;
  o[12] = v3.x; o[13] = v3.y; o[14] = v3.z; o[15] = v3.w;
}

__device__ __forceinline__ unsigned bf16bits(float x) {
  unsigned u = __float_as_uint(x);
  return (u + 0x7fffu + ((u >> 16) & 1u)) >> 16;  // RTNE
}

// packed bf16 pair via HW cvt (RTNE); lo16 = cvt(a), hi16 = cvt(b)
__device__ __forceinline__ unsigned cvtpk(float a, float b) {
  unsigned r;
  asm("v_cvt_pk_bf16_f32 %0, %1, %2" : "=v"(r) : "v"(a), "v"(b));
  return r;
}

__global__ void k_prep(const float* __restrict__ means, const float* __restrict__ lv,
                       const float* __restrict__ linit, const float* __restrict__ tbias,
                       const float* __restrict__ W1g, const float* __restrict__ b1g,
                       const float* __restrict__ W2g, const float* __restrict__ b2g,
                       float* __restrict__ P) {
  const int tid = threadIdx.x;  // 256; all write ranges disjoint
  if (tid < 80) {
    const float iv = __expf(-lv[tid]);
    P[L_QA + tid] = -0.5f * kL2E * iv;
    P[L_QB + tid] = kL2E * means[tid] * iv;
  }
  if (tid >= 80 && tid < 85) {
    const int s = tid - 80;
    float acc = 0.f;
#pragma unroll
    for (int d = 0; d < 16; ++d) {
      const float lvv = lv[s * 16 + d], mm = means[s * 16 + d];
      acc += lvv + mm * mm * __expf(-lvv);
    }
    P[L_QC + s] = -0.5f * kL2E * (29.406033062549525f + acc);  // 16*ln(2pi)+...
    const float l0 = linit[0], l1 = linit[1], l2 = linit[2], l3 = linit[3],
                l4 = linit[4];
    const float m = max5(l0, l1, l2, l3, l4);
    const float se = __expf(l0 - m) + __expf(l1 - m) + __expf(l2 - m) +
                     __expf(l3 - m) + __expf(l4 - m);
    P[L_LN + s] = kL2E * (linit[s] - (m + __logf(se)));
  }
  if (tid < 200) P[L_W1 + tid] = (2.0f * kL2E) * W1g[tid];
  if (tid < 60) {
    const int r = tid / 12, h = tid - r * 12;
    P[L_B1 + tid] = (h < 10) ? (2.0f * kL2E) * b1g[r * 10 + h] : 0.f;
  }
  for (int i = tid; i < 300; i += 256) {
    const int r = i / 12, h = i - r * 12;
    float v;
    if (h < 10) v = -2.0f * kL2E * W2g[r * 10 + h];
    else if (h == 10) {
      float sw = 0.f;
#pragma unroll
      for (int hh = 0; hh < 10; ++hh) sw += W2g[r * 10 + hh];
      v = kL2E * (b2g[r] + tbias[r] + sw);
    } else v = 0.f;
    P[L_W2 + i] = v;
  }
  if (tid >= 88 && tid < 88 + (P_TOT - 736)) P[736 + tid - 88] = 0.f;  // pad
}

// E_t = softmax(logits) * diag(exp2(le - c)); expanded quadratic emission,
// tanh folded into W2'.  All param reads are broadcast float4/float2.
__device__ __forceinline__ void buildE(const float* __restrict__ obs,
                                       const float* __restrict__ feat,
                                       const float* __restrict__ p,
                                       size_t t, float E[25], float& c) {
  float o[16], o2[16];
  loadObs(obs + t * kD, o);
#pragma unroll
  for (int d = 0; d < 16; ++d) o2[d] = o[d] * o[d];
  float le[5];
#pragma unroll
  for (int s = 0; s < 5; ++s) {
    float acc = p[L_QC + s];
#pragma unroll
    for (int dq = 0; dq < 4; ++dq) {
      const float4 qa = *reinterpret_cast<const float4*>(p + L_QA + s * 16 + dq * 4);
      const float4 qb = *reinterpret_cast<const float4*>(p + L_QB + s * 16 + dq * 4);
      acc = fmaf(o2[dq * 4 + 0], qa.x, acc); acc = fmaf(o[dq * 4 + 0], qb.x, acc);
      acc = fmaf(o2[dq * 4 + 1], qa.y, acc); acc = fmaf(o[dq * 4 + 1], qb.y, acc);
      acc = fmaf(o2[dq * 4 + 2], qa.z, acc); acc = fmaf(o[dq * 4 + 2], qb.z, acc);
      acc = fmaf(o2[dq * 4 + 3], qa.w, acc); acc = fmaf(o[dq * 4 + 3], qb.w, acc);
    }
    le[s] = acc;
  }
  c = max5(le[0], le[1], le[2], le[3], le[4]);
  float eml[5];
#pragma unroll
  for (int j = 0; j < 5; ++j) eml[j] = exp2f(le[j] - c);
  const float4 f = *reinterpret_cast<const float4*>(feat + t * 4);
#pragma unroll
  for (int i = 0; i < 5; ++i) {
    const float4 bA = *reinterpret_cast<const float4*>(p + L_B1 + i * 12);
    const float4 bB = *reinterpret_cast<const float4*>(p + L_B1 + i * 12 + 4);
    const float2 bC = *reinterpret_cast<const float2*>(p + L_B1 + i * 12 + 8);
    const float bb[10] = {bA.x, bA.y, bA.z, bA.w, bB.x, bB.y, bB.z, bB.w, bC.x, bC.y};
    float hr[10];  // r = rcp(exp(2z)+1); tanh = 1-2r folded into W2'
#pragma unroll
    for (int h = 0; h < 10; ++h) {
      const float4 w = *reinterpret_cast<const float4*>(p + L_W1 + (i * 10 + h) * 4);
      float acc = bb[h];
      acc = fmaf(f.x, w.x, acc);
      acc = fmaf(f.y, w.y, acc);
      acc = fmaf(f.z, w.z, acc);
      acc = fmaf(f.w, w.w, acc);
      hr[h] = __builtin_amdgcn_rcpf(exp2f(acc) + 1.f);
    }
    float eg[5], se = 0.f;
#pragma unroll
    for (int j = 0; j < 5; ++j) {
      const float* wr = p + L_W2 + (i * 5 + j) * 12;
      const float4 w0 = *reinterpret_cast<const float4*>(wr);
      const float4 w1 = *reinterpret_cast<const float4*>(wr + 4);
      const float4 w2 = *reinterpret_cast<const float4*>(wr + 8);  // x=w8 y=w9 z=b'
      float acc = w2.z;
      acc = fmaf(hr[0], w0.x, acc); acc = fmaf(hr[1], w0.y, acc);
      acc = fmaf(hr[2], w0.z, acc); acc = fmaf(hr[3], w0.w, acc);
      acc = fmaf(hr[4], w1.x, acc); acc = fmaf(hr[5], w1.y, acc);
      acc = fmaf(hr[6], w1.z, acc); acc = fmaf(hr[7], w1.w, acc);
      acc = fmaf(hr[8], w2.x, acc); acc = fmaf(hr[9], w2.y, acc);
      eg[j] = exp2f(acc);
      se += eg[j];
    }
    const float rs = __builtin_amdgcn_rcpf(se);
#pragma unroll
    for (int j = 0; j < 5; ++j) E[i * 5 + j] = eg[j] * rs * eml[j];
  }
}

// t=0 pseudo-record: all rows = linear alpha0 (log2-scaled by c)
__device__ __forceinline__ void buildE0(const float* __restrict__ obs,
                                        const float* __restrict__ p, int b,
                                        float E[25], float& c) {
  float o[16], o2[16];
  loadObs(obs + (size_t)b * kT * kD, o);
#pragma unroll
  for (int d = 0; d < 16; ++d) o2[d] = o[d] * o[d];
  float v[5];
#pragma unroll
  for (int s = 0; s < 5; ++s) {
    float acc = p[L_QC + s];
#pragma unroll
    for (int dq = 0; dq < 4; ++dq) {
      const float4 qa = *reinterpret_cast<const float4*>(p + L_QA + s * 16 + dq * 4);
      const float4 qb = *reinterpret_cast<const float4*>(p + L_QB + s * 16 + dq * 4);
      acc = fmaf(o2[dq * 4 + 0], qa.x, acc); acc = fmaf(o[dq * 4 + 0], qb.x, acc);
      acc = fmaf(o2[dq * 4 + 1], qa.y, acc); acc = fmaf(o[dq * 4 + 1], qb.y, acc);
      acc = fmaf(o2[dq * 4 + 2], qa.z, acc); acc = fmaf(o[dq * 4 + 2], qb.z, acc);
      acc = fmaf(o2[dq * 4 + 3], qa.w, acc); acc = fmaf(o[dq * 4 + 3], qb.w, acc);
    }
    v[s] = acc + p[L_LN + s];
  }
  c = max5(v[0], v[1], v[2], v[3], v[4]);
  float e5[5];
#pragma unroll
  for (int j = 0; j < 5; ++j) e5[j] = 0.2f * exp2f(v[j] - c);
#pragma unroll
  for (int i = 0; i < 5; ++i)
#pragma unroll
    for (int j = 0; j < 5; ++j) E[i * 5 + j] = e5[j];
}

// swizzled LDS tile: record r at row r, 32 cols, col(e) = ((r>>3)+((r&3)<<3)+e)&31
template <bool STORE_E>
__global__ __launch_bounds__(256, 4) void k_build(
    const float* __restrict__ obs, const float* __restrict__ feat,
    const float* __restrict__ P, float* __restrict__ Rg,
    uint4* __restrict__ wsE) {
  __shared__ __align__(16) float p[P_TOT];
  __shared__ float sw[kTile * 32];  // 32 KB
  if (threadIdx.x < P_TOT / 4)
    reinterpret_cast<float4*>(p)[threadIdx.x] =
        reinterpret_cast<const float4*>(P)[threadIdx.x];
  __syncthreads();
  const int b = blockIdx.y, tile = blockIdx.x, tid = threadIdx.x;
  const int t = tile * kTile + tid;
  const size_t gt = (size_t)b * kT + t;
  float E[25], c;
  if (t == 0) buildE0(obs, p, b, E, c);
  else buildE(obs, feat, p, gt, E, c);
  if (STORE_E) {
    const unsigned cb = __float_as_uint(c);
    uint4* wp = wsE + gt * 4;
    wp[0] = make_uint4(cvtpk(E[0], E[1]), cvtpk(E[2], E[3]),
                       cvtpk(E[4], E[5]), cvtpk(E[6], E[7]));
    wp[1] = make_uint4(cvtpk(E[8], E[9]), cvtpk(E[10], E[11]),
                       cvtpk(E[12], E[13]), cvtpk(E[14], E[15]));
    wp[2] = make_uint4(cvtpk(E[16], E[17]), cvtpk(E[18], E[19]),
                       cvtpk(E[20], E[21]), cvtpk(E[22], E[23]));
    wp[3] = make_uint4(bf16bits(E[24]) | (cb << 16), cb >> 16, 0u, 0u);
  }
  {
    const int base = tid * 32;
    const int off = (tid >> 3) + ((tid & 3) << 3);
#pragma unroll
    for (int e = 0; e < 25; ++e) sw[base + ((off + e) & 31)] = E[e];
    sw[base + ((off + 25) & 31)] = c;
  }
  __syncthreads();
  // row-parallel fold: 8 lanes per chunk, lane ri owns row ri (ri<5 active)
  const int chunk = tid >> 3, ri = tid & 7;
  float R[5], sc;
  {
    const int base = (chunk * 8) * 32, off = chunk;
#pragma unroll
    for (int m = 0; m < 5; ++m) R[m] = sw[base + ((off + ri * 5 + m) & 31)];
    sc = sw[base + ((off + 25) & 31)];
  }
#pragma unroll 1
  for (int k = 1; k < 8; ++k) {
    const int base = (chunk * 8 + k) * 32, off = chunk + ((k & 3) << 3);
    float Ek[25];
#pragma unroll
    for (int e = 0; e < 25; ++e) Ek[e] = sw[base + ((off + e) & 31)];
    sc += sw[base + ((off + 25) & 31)];
    float nR[5];
#pragma unroll
    for (int j = 0; j < 5; ++j) {
      float acc = R[0] * Ek[j];
      acc = fmaf(R[1], Ek[5 + j], acc);
      acc = fmaf(R[2], Ek[10 + j], acc);
      acc = fmaf(R[3], Ek[15 + j], acc);
      acc = fmaf(R[4], Ek[20 + j], acc);
      nR[j] = acc;
    }
#pragma unroll
    for (int j = 0; j < 5; ++j) R[j] = nR[j];
    if ((k & 1) == 0 || k == 7) {  // rescale at k=2,4,6,7
      float rm = (ri < 5) ? max5(R[0], R[1], R[2], R[3], R[4]) : 0.f;
      rm = fmaxf(rm, __shfl_xor(rm, 1, 8));
      rm = fmaxf(rm, __shfl_xor(rm, 2, 8));
      rm = fmaxf(rm, __shfl_xor(rm, 4, 8));
      rm = fmaxf(rm, 1e-30f);
      const float r = __builtin_amdgcn_rcpf(rm);
#pragma unroll
      for (int j = 0; j < 5; ++j) R[j] *= r;
      sc += __log2f(rm);
    }
  }
  if (ri < 5) {
    float* outr = Rg + ((size_t)b * kNC + tile * kCPT + chunk) * 28 + ri * 5;
#pragma unroll
    for (int m = 0; m < 5; ++m) outr[m] = R[m];
    if (ri == 0) outr[25] = sc;
  }
}

// ---------- scan helpers (array forms proven fine in these kernels) ----------

__device__ __forceinline__ void matmat5(float R[25], const float E[25]) {
#pragma unroll
  for (int i = 0; i < 5; ++i) {
    const float r0 = R[i * 5 + 0], r1 = R[i * 5 + 1], r2 = R[i * 5 + 2];
    const float r3 = R[i * 5 + 3], r4 = R[i * 5 + 4];
#pragma unroll
    for (int j = 0; j < 5; ++j) {
      float acc = r0 * E[j];
      acc = fmaf(r1, E[5 + j], acc);
      acc = fmaf(r2, E[10 + j], acc);
      acc = fmaf(r3, E[15 + j], acc);
      acc = fmaf(r4, E[20 + j], acc);
      R[i * 5 + j] = acc;
    }
  }
}

__device__ __forceinline__ void rescale25a(float R[25], float& sc) {
  float m = R[0];
#pragma unroll
  for (int e = 1; e < 25; ++e) m = fmaxf(m, R[e]);
  m = fmaxf(m, 1e-30f);
  const float r = __builtin_amdgcn_rcpf(m);
#pragma unroll
  for (int e = 0; e < 25; ++e) R[e] *= r;
  sc += __log2f(m);
}

__device__ __forceinline__ void vecmat5(float a[5], const float M[25]) {
  float o[5];
#pragma unroll
  for (int j = 0; j < 5; ++j) {
    float acc = a[0] * M[j];
    acc = fmaf(a[1], M[5 + j], acc);
    acc = fmaf(a[2], M[10 + j], acc);
    acc = fmaf(a[3], M[15 + j], acc);
    acc = fmaf(a[4], M[20 + j], acc);
    o[j] = acc;
  }
#pragma unroll
  for (int j = 0; j < 5; ++j) a[j] = o[j];
}

__device__ __forceinline__ void rescale5(float a[5], float& ls) {
  const float m = fmaxf(max5(a[0], a[1], a[2], a[3], a[4]), 1e-30f);
  const float r = __builtin_amdgcn_rcpf(m);
#pragma unroll
  for (int j = 0; j < 5; ++j) a[j] *= r;
  ls += __log2f(m);
}

// one block per b: group products, group scan (LL), within-group scan (start)
__global__ __launch_bounds__(256) void k_scan(const float* __restrict__ Rg,
                                              float* __restrict__ start,
                                              float* __restrict__ out) {
  __shared__ float sR[kNC * 32];  // 64 KB, swizzled: col=(rec+(rec>>4)+e)&31
  __shared__ float sP[kNG * 28];
  __shared__ float sA[kNG * 8];
  const int b = blockIdx.x, tid = threadIdx.x;
#pragma unroll
  for (int r = 0; r < 2; ++r) {
    const int rec = r * 256 + tid;
    const float4* src = reinterpret_cast<const float4*>(Rg + ((size_t)b * kNC + rec) * 28);
    float4 q[7];
#pragma unroll
    for (int i = 0; i < 7; ++i) q[i] = src[i];
    const float* v = reinterpret_cast<const float*>(q);
    const int base = rec * 32, off = rec + (rec >> 4);
#pragma unroll
    for (int e = 0; e < 26; ++e) sR[base + ((off + e) & 31)] = v[e];
  }
  __syncthreads();
  if (tid < kNG) {
    const int g = tid;
    float P[25], psc;
    {
      const int rec = g * kG, base = rec * 32, off = rec + (rec >> 4);
#pragma unroll
      for (int e = 0; e < 25; ++e) P[e] = sR[base + ((off + e) & 31)];
      psc = sR[base + ((off + 25) & 31)];
    }
#pragma unroll 1
    for (int k = 1; k < kG; ++k) {
      const int rec = g * kG + k, base = rec * 32, off = rec + (rec >> 4);
      float M[25];
#pragma unroll
      for (int e = 0; e < 25; ++e) M[e] = sR[base + ((off + e) & 31)];
      psc += sR[base + ((off + 25) & 31)];
      matmat5(P, M);
      if (k & 1) rescale25a(P, psc);
    }
#pragma unroll
    for (int e = 0; e < 25; ++e) sP[g * 28 + e] = P[e];
    sP[g * 28 + 25] = psc;
  }
  __syncthreads();
  if (tid == 0) {
    float a[5] = {1.f, 1.f, 1.f, 1.f, 1.f};
    float ls = 0.f;
#pragma unroll 1
    for (int g = 0; g < kNG; ++g) {
#pragma unroll
      for (int s = 0; s < 5; ++s) sA[g * 8 + s] = a[s];
      sA[g * 8 + 5] = ls;
      float M[25];
#pragma unroll
      for (int e = 0; e < 25; ++e) M[e] = sP[g * 28 + e];
      vecmat5(a, M);
      ls += sP[g * 28 + 25];
      rescale5(a, ls);
    }
    out[b] = (__log2f(a[0] + a[1] + a[2] + a[3] + a[4]) + ls) * kLn2;
  }
  __syncthreads();
  if (tid < kNG) {
    const int g = tid;
    float a[5], ls;
#pragma unroll
    for (int s = 0; s < 5; ++s) a[s] = sA[g * 8 + s];
    ls = sA[g * 8 + 5];
#pragma unroll 1
    for (int k = 0; k < kG; ++k) {
      const int cc = g * kG + k;
      float* st = start + ((size_t)b * kNC + cc) * 8;
      reinterpret_cast<float4*>(st)[0] = make_float4(a[0], a[1], a[2], a[3]);
      reinterpret_cast<float4*>(st)[1] = make_float4(a[4], ls, 0.f, 0.f);
      const int base = cc * 32, off = cc + (cc >> 4);
      float M[25];
#pragma unroll
      for (int e = 0; e < 25; ++e) M[e] = sR[base + ((off + e) & 31)];
      ls += sR[base + ((off + 25) & 31)];
      vecmat5(a, M);
      rescale5(a, ls);
    }
  }
}

// stream bf16 E records; one lane per chunk (8 steps)
__global__ __launch_bounds__(256) void k_alpha_a(const uint4* __restrict__ wsE,
                                                 const float* __restrict__ start,
                                                 float* __restrict__ outp) {
  const int gc = blockIdx.x * 256 + threadIdx.x;  // kB*kNC
  const int b = gc >> 9, cc = gc & (kNC - 1);
  const float* st = start + (size_t)gc * 8;
  const float4 s0 = reinterpret_cast<const float4*>(st)[0];
  const float4 s1 = reinterpret_cast<const float4*>(st)[1];
  float a[5] = {s0.x, s0.y, s0.z, s0.w, s1.x};
  float ls = s1.y;
  float ov[40];
  const uint4* ep = wsE + ((size_t)b * kT + (size_t)cc * kC) * 4;
#pragma unroll
  for (int k = 0; k < 8; ++k) {
    uint4 q0 = ep[k * 4], q1 = ep[k * 4 + 1], q2 = ep[k * 4 + 2], q3 = ep[k * 4 + 3];
    unsigned d[14] = {q0.x, q0.y, q0.z, q0.w, q1.x, q1.y, q1.z, q1.w,
                      q2.x, q2.y, q2.z, q2.w, q3.x, q3.y};
    float E[25];
#pragma unroll
    for (int q = 0; q < 12; ++q) {
      E[2 * q]     = __uint_as_float(d[q] << 16);
      E[2 * q + 1] = __uint_as_float(d[q] & 0xffff0000u);
    }
    E[24] = __uint_as_float(d[12] << 16);
    const float cst = __uint_as_float((d[12] >> 16) | (d[13] << 16));
    float o[5];
#pragma unroll
    for (int j = 0; j < 5; ++j) {
      float acc = a[0] * E[j];
      acc = fmaf(a[1], E[5 + j], acc);
      acc = fmaf(a[2], E[10 + j], acc);
      acc = fmaf(a[3], E[15 + j], acc);
      acc = fmaf(a[4], E[20 + j], acc);
      o[j] = acc;
    }
    ls += cst;
    float L[5];
#pragma unroll
    for (int j = 0; j < 5; ++j) L[j] = __log2f(o[j]);
#pragma unroll
    for (int j = 0; j < 5; ++j) ov[k * 5 + j] = (L[j] + ls) * kLn2;
    const float lm = max5(L[0], L[1], L[2], L[3], L[4]);
    const float m = fmaxf(max5(o[0], o[1], o[2], o[3], o[4]), 1e-30f);
    const float r = __builtin_amdgcn_rcpf(m);
#pragma unroll
    for (int j = 0; j < 5; ++j) a[j] = o[j] * r;
    ls += lm;
  }
  float4* w = reinterpret_cast<float4*>(outp + kB + ((size_t)b * kT + (size_t)cc * kC) * kS);
#pragma unroll
  for (int q = 0; q < 10; ++q)
    w[q] = make_float4(ov[q * 4], ov[q * 4 + 1], ov[q * 4 + 2], ov[q * 4 + 3]);
}

}  // namespace

extern "C" void kernel_launch(void* const* d_in, const int* in_sizes, int n_in,
                              void* d_out, int out_size, void* d_ws, size_t ws_size,
                              hipStream_t stream) {
  (void)in_sizes; (void)n_in; (void)out_size; (void)ws_size;
  const float* obs   = (const float*)d_in[0];
  const float* feat  = (const float*)d_in[1];
  const float* means = (const float*)d_in[2];
  const float* lv    = (const float*)d_in[3];
  const float* linit = (const float*)d_in[4];
  const float* tbias = (const float*)d_in[5];
  const float* W1g   = (const float*)d_in[6];
  const float* b1g   = (const float*)d_in[7];
  const float* W2g   = (const float*)d_in[8];
  const float* b2g   = (const float*)d_in[9];
  float* out = (float*)d_out;

  // ws layout (floats): P 1024 | Rg kB*kNC*28 | start kB*kNC*8 | wsE (bytes)
  float* P     = (float*)d_ws;
  float* Rg    = P + P_RSV;
  float* start = Rg + (size_t)kB * kNC * 28;
  uint4* wsE   = reinterpret_cast<uint4*>(start + (size_t)kB * kNC * 8);

  k_prep<<<1, 256, 0, stream>>>(means, lv, linit, tbias, W1g, b1g, W2g, b2g, P);
  dim3 gridB(kT / kTile, kB);
  k_build<true><<<gridB, kTile, 0, stream>>>(obs, feat, P, Rg, wsE);
  k_scan<<<kB, 256, 0, stream>>>(Rg, start, out);
  k_alpha_a<<<(kB * kNC) / 256, 256, 0, stream>>>(wsE, start, out);
}

// Round 11
// 115.563 us; speedup vs baseline: 6.4342x; 1.0799x over previous
//
#include <hip/hip_runtime.h>
#include <math.h>

// MarketRegimeHMM forward via chunked associative scan — linear semiring,
// base-2 scales.  R10 = the proven R3/R10 phase-split skeleton (build phase
// holds E only, fold phase holds R-rows only; never spills) + two local
// instruction diets:
//   1. RAW transcendentals: __builtin_amdgcn_exp2f / _logf (bare v_exp/v_log;
//      HIP's exp2f is OCML ~5 instrs — this was R4's hidden regression).
//   2. f16 v_dot2_f32_f16 for the MLP GEMVs (W1: 2 fdot2, W2: 5 fdot2),
//      weights pre-packed half2 in k_prep, hr/f packed via cvt_pkrtz.
//      Emission stays f32 (precision-critical).
//
//   k_prep  : 1 block; params -> vector layout (f32 emission + half2 MLP).
//   k_build : 256 t per block; thread t builds E_t; swizzled LDS transpose;
//             8 lanes/chunk row-parallel fold of 8 steps -> R[b][c].
//   k_scan  : one block per b; 512-record scan -> start[b][c], LL[b].
//   k_alpha : one lane per chunk: stream bf16 E, 25 FMA + 5 log2 per t.

namespace {

constexpr int kS = 5, kD = 16, kB = 256, kT = 4096;
constexpr int kC = 8, kNC = 512;     // chunks per batch element
constexpr int kTile = 256, kCPT = 32;
constexpr int kG = 16, kNG = 32;

constexpr float kL2E = 1.4426950408889634f;  // 1/ln2
constexpr float kLn2 = 0.6931471805599453f;

// param layout (floats), all vector-read aligned:
constexpr int L_QA  = 0;    // 80  -0.5*inv_v/ln2           [s*16+d] float4
constexpr int L_QB  = 80;   // 80  mu*inv_v/ln2             [s*16+d] float4
constexpr int L_QC  = 160;  // 5   -0.5/ln2*(16ln2pi + sum(lv + iv*mu^2)) (pad->168)
constexpr int L_LN  = 168;  // 5   log2_softmax(log_initial) (pad->176)
constexpr int L_W1H = 176;  // 100 half2 pairs of (2/ln2)*W1: [i*20 + h*2 + {01,23}]
constexpr int L_B1  = 276;  // 60  (2/ln2)*b1, rows of 12    f4,f4,f2
constexpr int L_W2H = 336;  // 200 rows of 8: [0..4]=half2 of -2*W2/ln2 pairs,
                            //     [5]=f32 (b2+tb+sum W2)/ln2, [6,7]=0
constexpr int P_TOT = 544;   // staged floats
constexpr int P_RSV = 1024;  // reserved in ws

typedef __fp16 half2_t __attribute__((ext_vector_type(2)));

#if __has_builtin(__builtin_amdgcn_exp2f)
__device__ __forceinline__ float ex2(float x) { return __builtin_amdgcn_exp2f(x); }
#else
__device__ __forceinline__ float ex2(float x) { return exp2f(x); }
#endif
#if __has_builtin(__builtin_amdgcn_logf)
__device__ __forceinline__ float lg2(float x) { return __builtin_amdgcn_logf(x); }
#else
__device__ __forceinline__ float lg2(float x) { return __log2f(x); }
#endif

__device__ __forceinline__ unsigned pkh(float a, float b) {
  return __builtin_bit_cast(unsigned, __builtin_amdgcn_cvt_pkrtz(a, b));
}

#if __has_builtin(__builtin_amdgcn_fdot2)
__device__ __forceinline__ float fdot2u(unsigned w, unsigned x, float acc) {
  return __builtin_amdgcn_fdot2(__builtin_bit_cast(half2_t, w),
                                __builtin_bit_cast(half2_t, x), acc, false);
}
#else
__device__ __forceinline__ float fdot2u(unsigned w, unsigned x, float acc) {
  const half2_t hw = __builtin_bit_cast(half2_t, w);
  const half2_t hx = __builtin_bit_cast(half2_t, x);
  return acc + (float)hw.x * (float)hx.x + (float)hw.y * (float)hx.y;
}
#endif

__device__ __forceinline__ float max5(float a0, float a1, float a2, float a3, float a4) {
  return fmaxf(fmaxf(fmaxf(a0, a1), fmaxf(a2, a3)), a4);
}

__device__ __forceinline__ void loadObs(const float* __restrict__ obs_bt, float* o) {
  const float4* o4 = reinterpret_cast<const float4*>(obs_bt);
  float4 v0 = o4[0], v1 = o4[1], v2 = o4[2], v3 = o4[3];
  o[0] = v0.x; o[1] = v0.y; o[2] = v0.z; o[3] = v0.w;
  o[4] = v1.x; o[5] = v1.y; o[6] = v1.z; o[7] = v1.w;
  o[8] = v2.x; o[9] = v2.y; o[10] = v2.z; o[11] = v2.w;
  o[12] = v3.x; o[13] = v3.y; o[14] = v3.z; o[15] = v3.w;
}

__device__ __forceinline__ unsigned bf16bits(float x) {
  unsigned u = __float_as_uint(x);
  return (u + 0x7fffu + ((u >> 16) & 1u)) >> 16;  // RTNE
}

// packed bf16 pair via HW cvt (RTNE)
__device__ __forceinline__ unsigned cvtpk(float a, float b) {
  unsigned r;
  asm("v_cvt_pk_bf16_f32 %0, %1, %2" : "=v"(r) : "v"(a), "v"(b));
  return r;
}

__global__ void k_prep(const float* __restrict__ means, const float* __restrict__ lv,
                       const float* __restrict__ linit, const float* __restrict__ tbias,
                       const float* __restrict__ W1g, const float* __restrict__ b1g,
                       const float* __restrict__ W2g, const float* __restrict__ b2g,
                       float* __restrict__ P) {
  const int tid = threadIdx.x;  // 256; all write ranges disjoint
  if (tid < 80) {
    const float iv = __expf(-lv[tid]);
    P[L_QA + tid] = -0.5f * kL2E * iv;
    P[L_QB + tid] = kL2E * means[tid] * iv;
  }
  if (tid >= 80 && tid < 85) {
    const int s = tid - 80;
    float acc = 0.f;
#pragma unroll
    for (int d = 0; d < 16; ++d) {
      const float lvv = lv[s * 16 + d], mm = means[s * 16 + d];
      acc += lvv + mm * mm * __expf(-lvv);
    }
    P[L_QC + s] = -0.5f * kL2E * (29.406033062549525f + acc);  // 16*ln(2pi)+...
    const float l0 = linit[0], l1 = linit[1], l2 = linit[2], l3 = linit[3],
                l4 = linit[4];
    const float m = max5(l0, l1, l2, l3, l4);
    const float se = __expf(l0 - m) + __expf(l1 - m) + __expf(l2 - m) +
                     __expf(l3 - m) + __expf(l4 - m);
    P[L_LN + s] = kL2E * (linit[s] - (m + __logf(se)));
  }
  if (tid < 100) {  // W1H: half2 pairs of (2/ln2)*W1
    const int i = tid / 20, rem = tid - i * 20, h = rem >> 1, part = rem & 1;
    const int base = (i * 10 + h) * 4 + part * 2;
    P[L_W1H + tid] = __uint_as_float(pkh((2.0f * kL2E) * W1g[base],
                                         (2.0f * kL2E) * W1g[base + 1]));
  }
  if (tid < 60) {  // B1 rows of 12
    const int r = tid / 12, h = tid - r * 12;
    P[L_B1 + tid] = (h < 10) ? (2.0f * kL2E) * b1g[r * 10 + h] : 0.f;
  }
  if (tid < 200) {  // W2H rows of 8
    const int r = tid >> 3, s = tid & 7;
    float v = 0.f;
    if (s < 5) {
      v = __uint_as_float(pkh(-2.0f * kL2E * W2g[r * 10 + 2 * s],
                              -2.0f * kL2E * W2g[r * 10 + 2 * s + 1]));
    } else if (s == 5) {
      float sw = 0.f;
#pragma unroll
      for (int hh = 0; hh < 10; ++hh) sw += W2g[r * 10 + hh];
      v = kL2E * (b2g[r] + tbias[r] + sw);
    }
    P[L_W2H + tid] = v;
  }
  if (tid < 3) { P[165 + tid] = 0.f; P[173 + tid] = 0.f; }  // pads
  if (tid < 8) P[536 + tid] = 0.f;
}

// E_t = softmax(logits) * diag(exp2(le - c)); f32 emission, f16-dot2 MLP.
__device__ __forceinline__ void buildE(const float* __restrict__ obs,
                                       const float* __restrict__ feat,
                                       const float* __restrict__ p,
                                       size_t t, float E[25], float& c) {
  float o[16], o2[16];
  loadObs(obs + t * kD, o);
#pragma unroll
  for (int d = 0; d < 16; ++d) o2[d] = o[d] * o[d];
  float le[5];
#pragma unroll
  for (int s = 0; s < 5; ++s) {
    float acc = p[L_QC + s];
#pragma unroll
    for (int dq = 0; dq < 4; ++dq) {
      const float4 qa = *reinterpret_cast<const float4*>(p + L_QA + s * 16 + dq * 4);
      const float4 qb = *reinterpret_cast<const float4*>(p + L_QB + s * 16 + dq * 4);
      acc = fmaf(o2[dq * 4 + 0], qa.x, acc); acc = fmaf(o[dq * 4 + 0], qb.x, acc);
      acc = fmaf(o2[dq * 4 + 1], qa.y, acc); acc = fmaf(o[dq * 4 + 1], qb.y, acc);
      acc = fmaf(o2[dq * 4 + 2], qa.z, acc); acc = fmaf(o[dq * 4 + 2], qb.z, acc);
      acc = fmaf(o2[dq * 4 + 3], qa.w, acc); acc = fmaf(o[dq * 4 + 3], qb.w, acc);
    }
    le[s] = acc;
  }
  c = max5(le[0], le[1], le[2], le[3], le[4]);
  float eml[5];
#pragma unroll
  for (int j = 0; j < 5; ++j) eml[j] = ex2(le[j] - c);
  const float4 f = *reinterpret_cast<const float4*>(feat + t * 4);
  const unsigned f01 = pkh(f.x, f.y), f23 = pkh(f.z, f.w);
#pragma unroll
  for (int i = 0; i < 5; ++i) {
    const float4 bA = *reinterpret_cast<const float4*>(p + L_B1 + i * 12);
    const float4 bB = *reinterpret_cast<const float4*>(p + L_B1 + i * 12 + 4);
    const float2 bC = *reinterpret_cast<const float2*>(p + L_B1 + i * 12 + 8);
    const uint4 wa = *reinterpret_cast<const uint4*>(p + L_W1H + i * 20);
    const uint4 wb = *reinterpret_cast<const uint4*>(p + L_W1H + i * 20 + 4);
    const uint4 wc = *reinterpret_cast<const uint4*>(p + L_W1H + i * 20 + 8);
    const uint4 wd = *reinterpret_cast<const uint4*>(p + L_W1H + i * 20 + 12);
    const uint4 we = *reinterpret_cast<const uint4*>(p + L_W1H + i * 20 + 16);
    // r = rcp(exp(2z)+1); tanh = 1-2r folded into W2'
    const float r0 = __builtin_amdgcn_rcpf(ex2(fdot2u(wa.y, f23, fdot2u(wa.x, f01, bA.x))) + 1.f);
    const float r1 = __builtin_amdgcn_rcpf(ex2(fdot2u(wa.w, f23, fdot2u(wa.z, f01, bA.y))) + 1.f);
    const float r2 = __builtin_amdgcn_rcpf(ex2(fdot2u(wb.y, f23, fdot2u(wb.x, f01, bA.z))) + 1.f);
    const float r3 = __builtin_amdgcn_rcpf(ex2(fdot2u(wb.w, f23, fdot2u(wb.z, f01, bA.w))) + 1.f);
    const float r4 = __builtin_amdgcn_rcpf(ex2(fdot2u(wc.y, f23, fdot2u(wc.x, f01, bB.x))) + 1.f);
    const float r5 = __builtin_amdgcn_rcpf(ex2(fdot2u(wc.w, f23, fdot2u(wc.z, f01, bB.y))) + 1.f);
    const float r6 = __builtin_amdgcn_rcpf(ex2(fdot2u(wd.y, f23, fdot2u(wd.x, f01, bB.z))) + 1.f);
    const float r7 = __builtin_amdgcn_rcpf(ex2(fdot2u(wd.w, f23, fdot2u(wd.z, f01, bB.w))) + 1.f);
    const float r8 = __builtin_amdgcn_rcpf(ex2(fdot2u(we.y, f23, fdot2u(we.x, f01, bC.x))) + 1.f);
    const float r9 = __builtin_amdgcn_rcpf(ex2(fdot2u(we.w, f23, fdot2u(we.z, f01, bC.y))) + 1.f);
    const unsigned h01 = pkh(r0, r1), h23 = pkh(r2, r3), h45 = pkh(r4, r5),
                   h67 = pkh(r6, r7), h89 = pkh(r8, r9);
    float eg[5], se = 0.f;
#pragma unroll
    for (int j = 0; j < 5; ++j) {
      const uint4 v = *reinterpret_cast<const uint4*>(p + L_W2H + (i * 5 + j) * 8);
      const uint2 v2 = *reinterpret_cast<const uint2*>(p + L_W2H + (i * 5 + j) * 8 + 4);
      float acc = __uint_as_float(v2.y);
      acc = fdot2u(v.x, h01, acc);
      acc = fdot2u(v.y, h23, acc);
      acc = fdot2u(v.z, h45, acc);
      acc = fdot2u(v.w, h67, acc);
      acc = fdot2u(v2.x, h89, acc);
      eg[j] = ex2(acc);
      se += eg[j];
    }
    const float rs = __builtin_amdgcn_rcpf(se);
#pragma unroll
    for (int j = 0; j < 5; ++j) E[i * 5 + j] = eg[j] * rs * eml[j];
  }
}

// t=0 pseudo-record: all rows = linear alpha0 (log2-scaled by c)
__device__ __forceinline__ void buildE0(const float* __restrict__ obs,
                                        const float* __restrict__ p, int b,
                                        float E[25], float& c) {
  float o[16], o2[16];
  loadObs(obs + (size_t)b * kT * kD, o);
#pragma unroll
  for (int d = 0; d < 16; ++d) o2[d] = o[d] * o[d];
  float v[5];
#pragma unroll
  for (int s = 0; s < 5; ++s) {
    float acc = p[L_QC + s];
#pragma unroll
    for (int dq = 0; dq < 4; ++dq) {
      const float4 qa = *reinterpret_cast<const float4*>(p + L_QA + s * 16 + dq * 4);
      const float4 qb = *reinterpret_cast<const float4*>(p + L_QB + s * 16 + dq * 4);
      acc = fmaf(o2[dq * 4 + 0], qa.x, acc); acc = fmaf(o[dq * 4 + 0], qb.x, acc);
      acc = fmaf(o2[dq * 4 + 1], qa.y, acc); acc = fmaf(o[dq * 4 + 1], qb.y, acc);
      acc = fmaf(o2[dq * 4 + 2], qa.z, acc); acc = fmaf(o[dq * 4 + 2], qb.z, acc);
      acc = fmaf(o2[dq * 4 + 3], qa.w, acc); acc = fmaf(o[dq * 4 + 3], qb.w, acc);
    }
    v[s] = acc + p[L_LN + s];
  }
  c = max5(v[0], v[1], v[2], v[3], v[4]);
  float e5[5];
#pragma unroll
  for (int j = 0; j < 5; ++j) e5[j] = 0.2f * ex2(v[j] - c);
#pragma unroll
  for (int i = 0; i < 5; ++i)
#pragma unroll
    for (int j = 0; j < 5; ++j) E[i * 5 + j] = e5[j];
}

// swizzled LDS tile: record r at row r, 32 cols, col(e) = ((r>>3)+((r&3)<<3)+e)&31
template <bool STORE_E>
__global__ __launch_bounds__(256, 4) void k_build(
    const float* __restrict__ obs, const float* __restrict__ feat,
    const float* __restrict__ P, float* __restrict__ Rg,
    uint4* __restrict__ wsE) {
  __shared__ __align__(16) float p[P_TOT];
  __shared__ float sw[kTile * 32];  // 32 KB
  if (threadIdx.x < P_TOT / 4)
    reinterpret_cast<float4*>(p)[threadIdx.x] =
        reinterpret_cast<const float4*>(P)[threadIdx.x];
  __syncthreads();
  const int b = blockIdx.y, tile = blockIdx.x, tid = threadIdx.x;
  const int t = tile * kTile + tid;
  const size_t gt = (size_t)b * kT + t;
  float E[25], c;
  if (t == 0) buildE0(obs, p, b, E, c);
  else buildE(obs, feat, p, gt, E, c);
  if (STORE_E) {
    const unsigned cb = __float_as_uint(c);
    uint4* wp = wsE + gt * 4;
    wp[0] = make_uint4(cvtpk(E[0], E[1]), cvtpk(E[2], E[3]),
                       cvtpk(E[4], E[5]), cvtpk(E[6], E[7]));
    wp[1] = make_uint4(cvtpk(E[8], E[9]), cvtpk(E[10], E[11]),
                       cvtpk(E[12], E[13]), cvtpk(E[14], E[15]));
    wp[2] = make_uint4(cvtpk(E[16], E[17]), cvtpk(E[18], E[19]),
                       cvtpk(E[20], E[21]), cvtpk(E[22], E[23]));
    wp[3] = make_uint4(bf16bits(E[24]) | (cb << 16), cb >> 16, 0u, 0u);
  }
  {
    const int base = tid * 32;
    const int off = (tid >> 3) + ((tid & 3) << 3);
#pragma unroll
    for (int e = 0; e < 25; ++e) sw[base + ((off + e) & 31)] = E[e];
    sw[base + ((off + 25) & 31)] = c;
  }
  __syncthreads();
  // row-parallel fold: 8 lanes per chunk, lane ri owns row ri (ri<5 active)
  const int chunk = tid >> 3, ri = tid & 7;
  float R[5], sc;
  {
    const int base = (chunk * 8) * 32, off = chunk;
#pragma unroll
    for (int m = 0; m < 5; ++m) R[m] = sw[base + ((off + ri * 5 + m) & 31)];
    sc = sw[base + ((off + 25) & 31)];
  }
#pragma unroll 1
  for (int k = 1; k < 8; ++k) {
    const int base = (chunk * 8 + k) * 32, off = chunk + ((k & 3) << 3);
    float Ek[25];
#pragma unroll
    for (int e = 0; e < 25; ++e) Ek[e] = sw[base + ((off + e) & 31)];
    sc += sw[base + ((off + 25) & 31)];
    float nR[5];
#pragma unroll
    for (int j = 0; j < 5; ++j) {
      float acc = R[0] * Ek[j];
      acc = fmaf(R[1], Ek[5 + j], acc);
      acc = fmaf(R[2], Ek[10 + j], acc);
      acc = fmaf(R[3], Ek[15 + j], acc);
      acc = fmaf(R[4], Ek[20 + j], acc);
      nR[j] = acc;
    }
#pragma unroll
    for (int j = 0; j < 5; ++j) R[j] = nR[j];
    if ((k & 1) == 0 || k == 7) {  // rescale at k=2,4,6,7
      float rm = (ri < 5) ? max5(R[0], R[1], R[2], R[3], R[4]) : 0.f;
      rm = fmaxf(rm, __shfl_xor(rm, 1, 8));
      rm = fmaxf(rm, __shfl_xor(rm, 2, 8));
      rm = fmaxf(rm, __shfl_xor(rm, 4, 8));
      rm = fmaxf(rm, 1e-30f);
      const float r = __builtin_amdgcn_rcpf(rm);
#pragma unroll
      for (int j = 0; j < 5; ++j) R[j] *= r;
      sc += lg2(rm);
    }
  }
  if (ri < 5) {
    float* outr = Rg + ((size_t)b * kNC + tile * kCPT + chunk) * 28 + ri * 5;
#pragma unroll
    for (int m = 0; m < 5; ++m) outr[m] = R[m];
    if (ri == 0) outr[25] = sc;
  }
}

// ---------- scan helpers (array forms proven fine in these kernels) ----------

__device__ __forceinline__ void matmat5(float R[25], const float E[25]) {
#pragma unroll
  for (int i = 0; i < 5; ++i) {
    const float r0 = R[i * 5 + 0], r1 = R[i * 5 + 1], r2 = R[i * 5 + 2];
    const float r3 = R[i * 5 + 3], r4 = R[i * 5 + 4];
#pragma unroll
    for (int j = 0; j < 5; ++j) {
      float acc = r0 * E[j];
      acc = fmaf(r1, E[5 + j], acc);
      acc = fmaf(r2, E[10 + j], acc);
      acc = fmaf(r3, E[15 + j], acc);
      acc = fmaf(r4, E[20 + j], acc);
      R[i * 5 + j] = acc;
    }
  }
}

__device__ __forceinline__ void rescale25a(float R[25], float& sc) {
  float m = R[0];
#pragma unroll
  for (int e = 1; e < 25; ++e) m = fmaxf(m, R[e]);
  m = fmaxf(m, 1e-30f);
  const float r = __builtin_amdgcn_rcpf(m);
#pragma unroll
  for (int e = 0; e < 25; ++e) R[e] *= r;
  sc += lg2(m);
}

__device__ __forceinline__ void vecmat5(float a[5], const float M[25]) {
  float o[5];
#pragma unroll
  for (int j = 0; j < 5; ++j) {
    float acc = a[0] * M[j];
    acc = fmaf(a[1], M[5 + j], acc);
    acc = fmaf(a[2], M[10 + j], acc);
    acc = fmaf(a[3], M[15 + j], acc);
    acc = fmaf(a[4], M[20 + j], acc);
    o[j] = acc;
  }
#pragma unroll
  for (int j = 0; j < 5; ++j) a[j] = o[j];
}

__device__ __forceinline__ void rescale5(float a[5], float& ls) {
  const float m = fmaxf(max5(a[0], a[1], a[2], a[3], a[4]), 1e-30f);
  const float r = __builtin_amdgcn_rcpf(m);
#pragma unroll
  for (int j = 0; j < 5; ++j) a[j] *= r;
  ls += lg2(m);
}

// one block per b: group products, group scan (LL), within-group scan (start)
__global__ __launch_bounds__(256) void k_scan(const float* __restrict__ Rg,
                                              float* __restrict__ start,
                                              float* __restrict__ out) {
  __shared__ float sR[kNC * 32];  // 64 KB, swizzled: col=(rec+(rec>>4)+e)&31
  __shared__ float sP[kNG * 28];
  __shared__ float sA[kNG * 8];
  const int b = blockIdx.x, tid = threadIdx.x;
#pragma unroll
  for (int r = 0; r < 2; ++r) {
    const int rec = r * 256 + tid;
    const float4* src = reinterpret_cast<const float4*>(Rg + ((size_t)b * kNC + rec) * 28);
    float4 q[7];
#pragma unroll
    for (int i = 0; i < 7; ++i) q[i] = src[i];
    const float* v = reinterpret_cast<const float*>(q);
    const int base = rec * 32, off = rec + (rec >> 4);
#pragma unroll
    for (int e = 0; e < 26; ++e) sR[base + ((off + e) & 31)] = v[e];
  }
  __syncthreads();
  if (tid < kNG) {
    const int g = tid;
    float P[25], psc;
    {
      const int rec = g * kG, base = rec * 32, off = rec + (rec >> 4);
#pragma unroll
      for (int e = 0; e < 25; ++e) P[e] = sR[base + ((off + e) & 31)];
      psc = sR[base + ((off + 25) & 31)];
    }
#pragma unroll 1
    for (int k = 1; k < kG; ++k) {
      const int rec = g * kG + k, base = rec * 32, off = rec + (rec >> 4);
      float M[25];
#pragma unroll
      for (int e = 0; e < 25; ++e) M[e] = sR[base + ((off + e) & 31)];
      psc += sR[base + ((off + 25) & 31)];
      matmat5(P, M);
      if (k & 1) rescale25a(P, psc);
    }
#pragma unroll
    for (int e = 0; e < 25; ++e) sP[g * 28 + e] = P[e];
    sP[g * 28 + 25] = psc;
  }
  __syncthreads();
  if (tid == 0) {
    float a[5] = {1.f, 1.f, 1.f, 1.f, 1.f};
    float ls = 0.f;
#pragma unroll 1
    for (int g = 0; g < kNG; ++g) {
#pragma unroll
      for (int s = 0; s < 5; ++s) sA[g * 8 + s] = a[s];
      sA[g * 8 + 5] = ls;
      float M[25];
#pragma unroll
      for (int e = 0; e < 25; ++e) M[e] = sP[g * 28 + e];
      vecmat5(a, M);
      ls += sP[g * 28 + 25];
      rescale5(a, ls);
    }
    out[b] = (lg2(a[0] + a[1] + a[2] + a[3] + a[4]) + ls) * kLn2;
  }
  __syncthreads();
  if (tid < kNG) {
    const int g = tid;
    float a[5], ls;
#pragma unroll
    for (int s = 0; s < 5; ++s) a[s] = sA[g * 8 + s];
    ls = sA[g * 8 + 5];
#pragma unroll 1
    for (int k = 0; k < kG; ++k) {
      const int cc = g * kG + k;
      float* st = start + ((size_t)b * kNC + cc) * 8;
      reinterpret_cast<float4*>(st)[0] = make_float4(a[0], a[1], a[2], a[3]);
      reinterpret_cast<float4*>(st)[1] = make_float4(a[4], ls, 0.f, 0.f);
      const int base = cc * 32, off = cc + (cc >> 4);
      float M[25];
#pragma unroll
      for (int e = 0; e < 25; ++e) M[e] = sR[base + ((off + e) & 31)];
      ls += sR[base + ((off + 25) & 31)];
      vecmat5(a, M);
      rescale5(a, ls);
    }
  }
}

// stream bf16 E records; one lane per chunk (8 steps)
__global__ __launch_bounds__(256) void k_alpha_a(const uint4* __restrict__ wsE,
                                                 const float* __restrict__ start,
                                                 float* __restrict__ outp) {
  const int gc = blockIdx.x * 256 + threadIdx.x;  // kB*kNC
  const int b = gc >> 9, cc = gc & (kNC - 1);
  const float* st = start + (size_t)gc * 8;
  const float4 s0 = reinterpret_cast<const float4*>(st)[0];
  const float4 s1 = reinterpret_cast<const float4*>(st)[1];
  float a[5] = {s0.x, s0.y, s0.z, s0.w, s1.x};
  float ls = s1.y;
  float ov[40];
  const uint4* ep = wsE + ((size_t)b * kT + (size_t)cc * kC) * 4;
#pragma unroll
  for (int k = 0; k < 8; ++k) {
    uint4 q0 = ep[k * 4], q1 = ep[k * 4 + 1], q2 = ep[k * 4 + 2], q3 = ep[k * 4 + 3];
    unsigned d[14] = {q0.x, q0.y, q0.z, q0.w, q1.x, q1.y, q1.z, q1.w,
                      q2.x, q2.y, q2.z, q2.w, q3.x, q3.y};
    float E[25];
#pragma unroll
    for (int q = 0; q < 12; ++q) {
      E[2 * q]     = __uint_as_float(d[q] << 16);
      E[2 * q + 1] = __uint_as_float(d[q] & 0xffff0000u);
    }
    E[24] = __uint_as_float(d[12] << 16);
    const float cst = __uint_as_float((d[12] >> 16) | (d[13] << 16));
    float o[5];
#pragma unroll
    for (int j = 0; j < 5; ++j) {
      float acc = a[0] * E[j];
      acc = fmaf(a[1], E[5 + j], acc);
      acc = fmaf(a[2], E[10 + j], acc);
      acc = fmaf(a[3], E[15 + j], acc);
      acc = fmaf(a[4], E[20 + j], acc);
      o[j] = acc;
    }
    ls += cst;
    float L[5];
#pragma unroll
    for (int j = 0; j < 5; ++j) L[j] = lg2(o[j]);
#pragma unroll
    for (int j = 0; j < 5; ++j) ov[k * 5 + j] = (L[j] + ls) * kLn2;
    const float lm = max5(L[0], L[1], L[2], L[3], L[4]);
    const float m = fmaxf(max5(o[0], o[1], o[2], o[3], o[4]), 1e-30f);
    const float r = __builtin_amdgcn_rcpf(m);
#pragma unroll
    for (int j = 0; j < 5; ++j) a[j] = o[j] * r;
    ls += lm;
  }
  float4* w = reinterpret_cast<float4*>(outp + kB + ((size_t)b * kT + (size_t)cc * kC) * kS);
#pragma unroll
  for (int q = 0; q < 10; ++q)
    w[q] = make_float4(ov[q * 4], ov[q * 4 + 1], ov[q * 4 + 2], ov[q * 4 + 3]);
}

}  // namespace

extern "C" void kernel_launch(void* const* d_in, const int* in_sizes, int n_in,
                              void* d_out, int out_size, void* d_ws, size_t ws_size,
                              hipStream_t stream) {
  (void)in_sizes; (void)n_in; (void)out_size; (void)ws_size;
  const float* obs   = (const float*)d_in[0];
  const float* feat  = (const float*)d_in[1];
  const float* means = (const float*)d_in[2];
  const float* lv    = (const float*)d_in[3];
  const float* linit = (const float*)d_in[4];
  const float* tbias = (const float*)d_in[5];
  const float* W1g   = (const float*)d_in[6];
  const float* b1g   = (const float*)d_in[7];
  const float* W2g   = (const float*)d_in[8];
  const float* b2g   = (const float*)d_in[9];
  float* out = (float*)d_out;

  // ws layout (floats): P 1024 | Rg kB*kNC*28 | start kB*kNC*8 | wsE (bytes)
  float* P     = (float*)d_ws;
  float* Rg    = P + P_RSV;
  float* start = Rg + (size_t)kB * kNC * 28;
  uint4* wsE   = reinterpret_cast<uint4*>(start + (size_t)kB * kNC * 8);

  k_prep<<<1, 256, 0, stream>>>(means, lv, linit, tbias, W1g, b1g, W2g, b2g, P);
  dim3 gridB(kT / kTile, kB);
  k_build<true><<<gridB, kTile, 0, stream>>>(obs, feat, P, Rg, wsE);
  k_scan<<<kB, 256, 0, stream>>>(Rg, start, out);
  k_alpha_a<<<(kB * kNC) / 256, 256, 0, stream>>>(wsE, start, out);
}